// Round 21
// baseline (1062.183 us; speedup 1.0000x reference)
//
#include <hip/hip_runtime.h>
#include <hip/hip_bf16.h>
#include <hip/hip_fp16.h>
#include <math.h>

#define S_LEN 256
#define BATCH 64
#define EMB 300
#define HID 512
#define NCLS 46
#define NVAL 4
#define G4H 2048
#define KPAD 320
#define NPADC 256
#define EPSV 1e-8f
#define FSTR 16   // ints per flag slot (64B line)

using half8   = __attribute__((ext_vector_type(8))) _Float16;
using floatx4 = __attribute__((ext_vector_type(4))) float;

__device__ __forceinline__ float fsigm(float x) { return 1.f / (1.f + __expf(-x)); }
__device__ __forceinline__ float ftanh(float x) {
    float e2 = __expf(-2.f * x);
    return (1.f - e2) / (1.f + e2);
}
__device__ __forceinline__ float h2f(unsigned short u) {
    union { unsigned short s; _Float16 h; } cv; cv.s = u; return (float)cv.h;
}
__device__ __forceinline__ half8 pack8(const float* p) {
    float4 f0 = *(const float4*)p;
    float4 f1 = *(const float4*)(p + 4);
    half8 h;
    h[0] = (_Float16)f0.x; h[1] = (_Float16)f0.y; h[2] = (_Float16)f0.z; h[3] = (_Float16)f0.w;
    h[4] = (_Float16)f1.x; h[5] = (_Float16)f1.y; h[6] = (_Float16)f1.z; h[7] = (_Float16)f1.w;
    return h;
}
__device__ __forceinline__ void pollflag(const int* fp, int want) {
    int gd = 1 << 20;
    while (__hip_atomic_load(fp, __ATOMIC_RELAXED, __HIP_MEMORY_SCOPE_AGENT) < want && --gd)
        __builtin_amdgcn_s_sleep(1);
}

// ---------------- label: norm + fp16 convert + zero-pad ----------------
__global__ void k_lab(const float* __restrict__ label, float* __restrict__ ln,
                      unsigned short* __restrict__ Lh) {
    int r = blockIdx.x;
    int lane = threadIdx.x;
    float ss = 0.f;
    if (r < NCLS * NVAL) {
        const float* row = label + (size_t)r * EMB;
        for (int e = lane; e < 80; e += 64) {
            ushort4 o = {0, 0, 0, 0};
            if (e < 75) {
                float4 v = *(const float4*)(row + e * 4);
                ss += v.x * v.x + v.y * v.y + v.z * v.z + v.w * v.w;
                union { _Float16 h; unsigned short s; } a, b, cc, d;
                a.h = (_Float16)v.x; b.h = (_Float16)v.y; cc.h = (_Float16)v.z; d.h = (_Float16)v.w;
                o.x = a.s; o.y = b.s; o.z = cc.s; o.w = d.s;
            }
            *(ushort4*)(Lh + (size_t)r * KPAD + e * 4) = o;
        }
        #pragma unroll
        for (int off = 32; off; off >>= 1) ss += __shfl_down(ss, off);
        if (lane == 0) ln[r] = sqrtf(ss);
    } else {
        for (int e = lane; e < 80; e += 64) {
            ushort4 o = {0, 0, 0, 0};
            *(ushort4*)(Lh + (size_t)r * KPAD + e * 4) = o;
        }
    }
}

// ---------------- gather -> fp16 Xh + fp32 norms ----------------
__global__ __launch_bounds__(256) void k_gather(const int* __restrict__ seq,
                                                const float* __restrict__ emb,
                                                unsigned short* __restrict__ Xh,
                                                float* __restrict__ en) {
    int p = blockIdx.x * 4 + (threadIdx.x >> 6);
    int lane = threadIdx.x & 63;
    int row = seq[p];
    const float4* src = (const float4*)(emb + (size_t)row * EMB);
    float ss = 0.f;
    for (int e = lane; e < 80; e += 64) {
        ushort4 o = {0, 0, 0, 0};
        if (e < 75) {
            float4 v = src[e];
            ss += v.x * v.x + v.y * v.y + v.z * v.z + v.w * v.w;
            union { _Float16 h; unsigned short s; } a, b, cc, d;
            a.h = (_Float16)v.x; b.h = (_Float16)v.y; cc.h = (_Float16)v.z; d.h = (_Float16)v.w;
            o.x = a.s; o.y = b.s; o.z = cc.s; o.w = d.s;
        }
        *(ushort4*)(Xh + (size_t)p * KPAD + e * 4) = o;
    }
    #pragma unroll
    for (int off = 32; off; off >>= 1) ss += __shfl_down(ss, off);
    if (lane == 0) en[p] = sqrtf(ss);
}

// ---------------- merged MFMA GEMM: G0 (bx<16) | cos numerator (bx>=16) ----------------
__global__ __launch_bounds__(256) void k_gmm_all(const unsigned short* __restrict__ X,
                                                 const unsigned short* __restrict__ Wh0,
                                                 const unsigned short* __restrict__ Lh,
                                                 const float* __restrict__ b1,
                                                 const float* __restrict__ b2,
                                                 unsigned short* __restrict__ G0,
                                                 float* __restrict__ numG) {
    __shared__ __align__(16) char smem[20480];
    unsigned short (*Xs)[40] = (unsigned short(*)[40])smem;
    unsigned short (*Ws)[40] = (unsigned short(*)[40])(smem + 10240);

    int bx = blockIdx.x;
    bool iscos = bx >= 16;
    const unsigned short* W = iscos ? Lh : Wh0;
    int n0 = (iscos ? bx - 16 : bx) * 128;
    int m0 = blockIdx.y * 128;
    int tid = threadIdx.x;
    int w8 = tid >> 6, l = tid & 63, lj = l & 15, q8 = l >> 4;
    int wm = w8 & 1, wn = w8 >> 1;

    floatx4 acc[4][4];
    #pragma unroll
    for (int i = 0; i < 4; i++)
        #pragma unroll
        for (int j = 0; j < 4; j++) acc[i][j] = {0.f, 0.f, 0.f, 0.f};

    for (int k0 = 0; k0 < KPAD; k0 += 32) {
        #pragma unroll
        for (int i = 0; i < 2; i++) {
            int id = i * 256 + tid;
            int r = id >> 2, kc = (id & 3) * 8;
            *(uint4*)&Xs[r][kc] = *(const uint4*)&X[(size_t)(m0 + r) * KPAD + k0 + kc];
            *(uint4*)&Ws[r][kc] = *(const uint4*)&W[(size_t)(n0 + r) * KPAD + k0 + kc];
        }
        __syncthreads();
        half8 A[4], B[4];
        #pragma unroll
        for (int i = 0; i < 4; i++) A[i] = *(const half8*)&Xs[wm * 64 + i * 16 + lj][q8 * 8];
        #pragma unroll
        for (int j = 0; j < 4; j++) B[j] = *(const half8*)&Ws[wn * 64 + j * 16 + lj][q8 * 8];
        #pragma unroll
        for (int i = 0; i < 4; i++)
            #pragma unroll
            for (int j = 0; j < 4; j++)
                acc[i][j] = __builtin_amdgcn_mfma_f32_16x16x32_f16(A[i], B[j], acc[i][j], 0, 0, 0);
        __syncthreads();
    }

    #pragma unroll
    for (int j = 0; j < 4; j++) {
        int col = n0 + wn * 64 + j * 16 + lj;
        float bsum = iscos ? 0.f : (b1[col] + b2[col]);
        #pragma unroll
        for (int i = 0; i < 4; i++) {
            int row = m0 + wm * 64 + i * 16 + q8 * 4;
            #pragma unroll
            for (int reg = 0; reg < 4; reg++) {
                float v = acc[i][j][reg] + bsum;
                if (iscos) {
                    numG[(size_t)(row + reg) * NPADC + col] = v;
                } else {
                    union { _Float16 h; unsigned short s; } cv; cv.h = (_Float16)v;
                    G0[(size_t)(row + reg) * G4H + col] = cv.s;
                }
            }
        }
    }
}

// ---------------- match: max over (s,v) of num/(en*ln) ----------------
__global__ __launch_bounds__(256) void k_match(const float* __restrict__ num,
                                               const float* __restrict__ en,
                                               const float* __restrict__ ln,
                                               float* __restrict__ match) {
    int c = blockIdx.x, b = blockIdx.y;
    __shared__ float red[256];
    int s = threadIdx.x;
    float4 nv = *(const float4*)&num[((size_t)s * BATCH + b) * NPADC + c * 4];
    float enb = en[s * BATCH + b];
    float l0 = ln[c * 4 + 0], l1 = ln[c * 4 + 1], l2 = ln[c * 4 + 2], l3 = ln[c * 4 + 3];
    float m = nv.x / fmaxf(enb * l0, EPSV);
    m = fmaxf(m, nv.y / fmaxf(enb * l1, EPSV));
    m = fmaxf(m, nv.z / fmaxf(enb * l2, EPSV));
    m = fmaxf(m, nv.w / fmaxf(enb * l3, EPSV));
    red[s] = m;
    __syncthreads();
    for (int st = 128; st; st >>= 1) {
        if (s < st) red[s] = fmaxf(red[s], red[s + st]);
        __syncthreads();
    }
    if (s == 0) match[b * NCLS + c] = red[0];
}

// ---------------- fused 2-layer pipelined persistent LSTM ----------------
// R20 base + per-wave publish: each wave drains its OWN h-stores
// (s_waitcnt vmcnt(0)) and publishes a per-(role,wave) flag -- the block's
// trailing barrier is gone (2 barriers/step). Consumers poll the exact
// (role,wave) flag of their slice. Safety: hl reads end before barrier(2);
// gbuf reads@t end before each wave reaches barrier(1)@t+1.
// flags0: [8g][8r][8w], flags1: [8g][16r][4w], each slot FSTR ints (64B).
__global__ __launch_bounds__(512) void k_lstm_pipe(
    const float* __restrict__ w_hh0,
    const unsigned short* __restrict__ G0,   // [256][64][2048] fp16
    const float* __restrict__ w_ih1,
    const float* __restrict__ w_hh1,
    const float* __restrict__ b_ih1,
    const float* __restrict__ b_hh1,
    unsigned short* __restrict__ ring0,
    unsigned short* __restrict__ ring1,
    float* __restrict__ hlast,
    int* __restrict__ flags0,                // [512*FSTR]
    int* __restrict__ flags1)                // [512*FSTR]
{
    __shared__ __align__(16) char smem_raw[24576];
    int bid = blockIdx.x;
    int g = bid & 7;
    int tid = threadIdx.x;
    int w8 = tid >> 6, l = tid & 63, lj = l & 15, q8 = l >> 4;

    if (bid < 64) {
        // ================= LAYER 0 =================
        int r = bid >> 3;
        _Float16 (*hl)[520] = (_Float16(*)[520])smem_raw;
        float (*gbuf)[260] = (float(*)[260])(smem_raw + 8320);

        half8 B0[16], B1[16];
        {
            int lc0 = w8 * 32 + lj;
            int lc1 = w8 * 32 + 16 + lj;
            int wr0 = (lc0 >> 6) * 512 + r * 64 + (lc0 & 63);
            int wr1 = (lc1 >> 6) * 512 + r * 64 + (lc1 & 63);
            #pragma unroll
            for (int kk = 0; kk < 16; kk++) {
                B0[kk] = pack8(w_hh0 + (size_t)wr0 * 512 + kk * 32 + q8 * 8);
                B1[kk] = pack8(w_hh0 + (size_t)wr1 * 512 + kk * 32 + q8 * 8);
            }
        }
        int gb_ = tid >> 6, gj = tid & 63;
        int sb = tid >> 6, sk = (tid & 63) * 8;
        // source of my slice: role sk>>6, producer wave (=batch) sb
        const int* myflag0 = flags0 + (((g * 8 + (sk >> 6)) << 3) + sb) * FSTR;
        int* pubflag = flags0 + (((g * 8 + r) << 3) + w8) * FSTR;
        float cst = 0.f;

        for (int t = 0; t < S_LEN; t++) {
            const unsigned short* Gp = G0 + ((size_t)t * BATCH + g * 8 + gb_) * G4H + r * 64 + gj;
            float gv0 = h2f(Gp[0]), gv1 = h2f(Gp[512]), gv2 = h2f(Gp[1024]), gv3 = h2f(Gp[1536]);

            if (t > 0) {
                pollflag(myflag0, t);
                {
                    const unsigned long long* src = (const unsigned long long*)
                        (ring0 + ((size_t)(t - 1) * BATCH + g * 8 + sb) * HID + sk);
                    unsigned long long v0 = __hip_atomic_load(src,     __ATOMIC_RELAXED, __HIP_MEMORY_SCOPE_AGENT);
                    unsigned long long v1 = __hip_atomic_load(src + 1, __ATOMIC_RELAXED, __HIP_MEMORY_SCOPE_AGENT);
                    *(unsigned long long*)&hl[sb][sk]     = v0;
                    *(unsigned long long*)&hl[sb][sk + 4] = v1;
                }
                __syncthreads();                               // barrier 1: stage -> MFMA
                floatx4 acc0 = {0.f, 0.f, 0.f, 0.f}, acc1 = {0.f, 0.f, 0.f, 0.f};
                __builtin_amdgcn_s_setprio(1);
                #pragma unroll
                for (int kk = 0; kk < 16; kk++) {
                    half8 A = *(const half8*)&hl[l & 7][kk * 32 + q8 * 8];
                    acc0 = __builtin_amdgcn_mfma_f32_16x16x32_f16(A, B0[kk], acc0, 0, 0, 0);
                    acc1 = __builtin_amdgcn_mfma_f32_16x16x32_f16(A, B1[kk], acc1, 0, 0, 0);
                }
                __builtin_amdgcn_s_setprio(0);
                if (l < 32) {
                    #pragma unroll
                    for (int ri = 0; ri < 4; ri++) {
                        int row = q8 * 4 + ri;
                        gbuf[row][w8 * 32 + lj]      = acc0[ri];
                        gbuf[row][w8 * 32 + 16 + lj] = acc1[ri];
                    }
                }
                __syncthreads();                               // barrier 2: gbuf -> pointwise
            }

            float s_i = gv0 + (t ? gbuf[gb_][gj]       : 0.f);
            float s_f = gv1 + (t ? gbuf[gb_][64 + gj]  : 0.f);
            float s_g = gv2 + (t ? gbuf[gb_][128 + gj] : 0.f);
            float s_o = gv3 + (t ? gbuf[gb_][192 + gj] : 0.f);
            cst = fsigm(s_f) * cst + fsigm(s_i) * ftanh(s_g);
            float hv = fsigm(s_o) * ftanh(cst);

            union { unsigned short s; _Float16 h; } cv; cv.h = (_Float16)hv;
            unsigned int mine = cv.s;
            unsigned int other = (unsigned int)__shfl_xor((int)mine, 1);
            if (!(gj & 1)) {
                unsigned int pk = (mine & 0xFFFFu) | (other << 16);
                unsigned int* rp = (unsigned int*)ring0;
                __hip_atomic_store(rp + (((size_t)t * BATCH + g * 8 + gb_) * HID + r * 64 + gj) / 2,
                                   pk, __ATOMIC_RELAXED, __HIP_MEMORY_SCOPE_AGENT);
            }
            // per-wave publish: drain own stores, lane 0 raises this wave's flag
            asm volatile("s_waitcnt vmcnt(0)" ::: "memory");
            if ((tid & 63) == 0)
                __hip_atomic_store(pubflag, t + 1, __ATOMIC_RELAXED, __HIP_MEMORY_SCOPE_AGENT);
        }
    } else {
        // ================= LAYER 1 =================
        int rid = (bid - 64) >> 3;
        _Float16 (*hl0)[520] = (_Float16(*)[520])smem_raw;
        _Float16 (*hl1)[520] = (_Float16(*)[520])(smem_raw + 8320);
        float (*gbuf)[132] = (float(*)[132])(smem_raw + 16640);

        half8 Bin[16], Brec[16];
        {
            int gate = w8 >> 1;
            int wrow = gate * 512 + rid * 32 + (w8 & 1) * 16 + lj;
            #pragma unroll
            for (int kk = 0; kk < 16; kk++) {
                Bin[kk]  = pack8(w_ih1 + (size_t)wrow * 512 + kk * 32 + q8 * 8);
                Brec[kk] = pack8(w_hh1 + (size_t)wrow * 512 + kk * 32 + q8 * 8);
            }
        }
        float bi = 0.f, bf = 0.f, bgg = 0.f, bo = 0.f;
        if (tid < 256) {
            int u = tid & 31;
            int base = rid * 32 + u;
            bi  = b_ih1[base]        + b_hh1[base];
            bf  = b_ih1[512 + base]  + b_hh1[512 + base];
            bgg = b_ih1[1024 + base] + b_hh1[1024 + base];
            bo  = b_ih1[1536 + base] + b_hh1[1536 + base];
        }
        int sb = tid >> 6, sk = (tid & 63) * 8;
        const int* myflag0 = flags0 + (((g * 8  + (sk >> 6)) << 3) + sb) * FSTR;         // h0: role, wave=batch
        const int* myflag1 = flags1 + (((g * 16 + (sk >> 5)) << 2) + (sb >> 1)) * FSTR;  // h1: role, wave=batch/2
        int* pubflag = flags1 + (((g * 16 + rid) << 2) + w8) * FSTR;                     // waves 0-3 publish
        float cst = 0.f;

        for (int t = 0; t < S_LEN; t++) {
            pollflag(myflag0, t + 1);
            if (t > 0) pollflag(myflag1, t);
            {
                const unsigned long long* s0 = (const unsigned long long*)
                    (ring0 + ((size_t)t * BATCH + g * 8 + sb) * HID + sk);
                unsigned long long v0 = __hip_atomic_load(s0,     __ATOMIC_RELAXED, __HIP_MEMORY_SCOPE_AGENT);
                unsigned long long v1 = __hip_atomic_load(s0 + 1, __ATOMIC_RELAXED, __HIP_MEMORY_SCOPE_AGENT);
                *(unsigned long long*)&hl0[sb][sk]     = v0;
                *(unsigned long long*)&hl0[sb][sk + 4] = v1;
                if (t > 0) {
                    const unsigned long long* s1 = (const unsigned long long*)
                        (ring1 + ((size_t)(t - 1) * BATCH + g * 8 + sb) * HID + sk);
                    unsigned long long u0 = __hip_atomic_load(s1,     __ATOMIC_RELAXED, __HIP_MEMORY_SCOPE_AGENT);
                    unsigned long long u1 = __hip_atomic_load(s1 + 1, __ATOMIC_RELAXED, __HIP_MEMORY_SCOPE_AGENT);
                    *(unsigned long long*)&hl1[sb][sk]     = u0;
                    *(unsigned long long*)&hl1[sb][sk + 4] = u1;
                }
            }
            __syncthreads();                               // barrier 1

            floatx4 accA = {0.f, 0.f, 0.f, 0.f}, accB = {0.f, 0.f, 0.f, 0.f};
            __builtin_amdgcn_s_setprio(1);
            #pragma unroll
            for (int kk = 0; kk < 16; kk++) {
                half8 A0 = *(const half8*)&hl0[l & 7][kk * 32 + q8 * 8];
                accA = __builtin_amdgcn_mfma_f32_16x16x32_f16(A0, Bin[kk], accA, 0, 0, 0);
            }
            if (t > 0) {
                #pragma unroll
                for (int kk = 0; kk < 16; kk++) {
                    half8 A1 = *(const half8*)&hl1[l & 7][kk * 32 + q8 * 8];
                    accB = __builtin_amdgcn_mfma_f32_16x16x32_f16(A1, Brec[kk], accB, 0, 0, 0);
                }
            }
            __builtin_amdgcn_s_setprio(0);
            if (l < 32) {
                #pragma unroll
                for (int ri = 0; ri < 4; ri++) {
                    int row = q8 * 4 + ri;
                    gbuf[row][w8 * 16 + lj] = accA[ri] + accB[ri];
                }
            }
            __syncthreads();                               // barrier 2

            if (tid < 256) {
                int b = tid >> 5, u = tid & 31;
                float s_i = gbuf[b][u]      + bi;
                float s_f = gbuf[b][32 + u] + bf;
                float s_g = gbuf[b][64 + u] + bgg;
                float s_o = gbuf[b][96 + u] + bo;
                cst = fsigm(s_f) * cst + fsigm(s_i) * ftanh(s_g);
                float hv = fsigm(s_o) * ftanh(cst);

                union { unsigned short s; _Float16 h; } cv; cv.h = (_Float16)hv;
                unsigned int mine = cv.s;
                unsigned int other = (unsigned int)__shfl_xor((int)mine, 1);
                if (!(u & 1)) {
                    unsigned int pk = (mine & 0xFFFFu) | (other << 16);
                    unsigned int* rp = (unsigned int*)ring1;
                    __hip_atomic_store(rp + (((size_t)t * BATCH + g * 8 + b) * HID + rid * 32 + u) / 2,
                                       pk, __ATOMIC_RELAXED, __HIP_MEMORY_SCOPE_AGENT);
                }
                if (t == S_LEN - 1)
                    hlast[(g * 8 + b) * HID + rid * 32 + u] = hv;
            }
            // per-wave publish (waves 0-3 carry h1 stores)
            asm volatile("s_waitcnt vmcnt(0)" ::: "memory");
            if (tid < 256 && (tid & 63) == 0)
                __hip_atomic_store(pubflag, t + 1, __ATOMIC_RELAXED, __HIP_MEMORY_SCOPE_AGENT);
        }
    }
}

// ---------------- small GEMM ----------------
__global__ void k_small(const float* __restrict__ X, const float* __restrict__ W,
                        const float* __restrict__ bias, float* __restrict__ Y,
                        int N, int K) {
    int m = blockIdx.x;
    int n = blockIdx.y * 64 + threadIdx.x;
    if (n >= N) return;
    const float* x = X + (size_t)m * K;
    const float* w = W + (size_t)n * K;
    float s = bias[n];
    for (int k = 0; k < K; k++) s += x[k] * w[k];
    Y[(size_t)m * N + n] = s;
}

// ---------------- final head ----------------
__global__ void k_final(const float* __restrict__ match, const float* __restrict__ lout,
                        const float* __restrict__ W, const float* __restrict__ bias,
                        float* __restrict__ out) {
    int m = blockIdx.x;
    int n = threadIdx.x;
    if (n >= NCLS) return;
    const float* w = W + (size_t)n * (2 * NCLS);
    float s = bias[n];
    for (int k = 0; k < NCLS; k++) s += match[m * NCLS + k] * w[k];
    for (int k = 0; k < NCLS; k++) s += lout[m * NCLS + k] * w[NCLS + k];
    out[m * NCLS + n] = s;
}

// ---------------- w_ih0 fp32[2048][300] -> fp16[2048][320] zero-padded ----------------
__global__ __launch_bounds__(256) void k_cvtw(const float* __restrict__ in,
                                              unsigned short* __restrict__ out) {
    int r = blockIdx.x * 4 + (threadIdx.x >> 6);
    int lane = threadIdx.x & 63;
    for (int e = lane; e < 80; e += 64) {
        int c = e * 4;
        ushort4 o = {0, 0, 0, 0};
        if (c < EMB) {
            float4 v = *(const float4*)(in + (size_t)r * EMB + c);
            union { _Float16 h; unsigned short s; } a, b, cc, d;
            a.h = (_Float16)v.x; b.h = (_Float16)v.y; cc.h = (_Float16)v.z; d.h = (_Float16)v.w;
            o.x = a.s; o.y = b.s; o.z = cc.s; o.w = d.s;
        }
        *(ushort4*)(out + (size_t)r * KPAD + c) = o;
    }
}

extern "C" void kernel_launch(void* const* d_in, const int* in_sizes, int n_in,
                              void* d_out, int out_size, void* d_ws, size_t ws_size,
                              hipStream_t stream) {
    (void)in_sizes; (void)n_in; (void)out_size; (void)ws_size;
    const int*   seq    = (const int*)d_in[0];
    const float* emb    = (const float*)d_in[1];
    const float* w_ih0  = (const float*)d_in[2];
    const float* w_hh0  = (const float*)d_in[3];
    const float* b_ih0  = (const float*)d_in[4];
    const float* b_hh0  = (const float*)d_in[5];
    const float* w_ih1  = (const float*)d_in[6];
    const float* w_hh1  = (const float*)d_in[7];
    const float* b_ih1  = (const float*)d_in[8];
    const float* b_hh1  = (const float*)d_in[9];
    const float* lin_w  = (const float*)d_in[10];
    const float* lin_b  = (const float*)d_in[11];
    const float* out_w  = (const float*)d_in[12];
    const float* out_b  = (const float*)d_in[13];
    const float* pred_w = (const float*)d_in[14];
    const float* pred_b = (const float*)d_in[15];
    const float* label  = (const float*)d_in[16];

    const int M = S_LEN * BATCH;  // 16384
    float* ws = (float*)d_ws;
    size_t o = 0;
    unsigned short* G0 = (unsigned short*)(ws + o); o += (size_t)M * G4H / 2;
    unsigned short* ring0 = (unsigned short*)(ws + o); o += (size_t)M * HID / 2;
    unsigned short* ring1 = (unsigned short*)(ws + o); o += (size_t)M * HID / 2;
    float* h1last = ws + o; o += (size_t)BATCH * HID;
    float* en    = ws + o; o += M;
    float* ln    = ws + o; o += 256;
    float* match = ws + o; o += 3072;
    float* feat  = ws + o; o += (size_t)BATCH * HID;
    float* lout  = ws + o; o += 3072;
    int*   flags0 = (int*)(ws + o); o += 512 * FSTR;
    int*   flags1 = (int*)(ws + o); o += 512 * FSTR;
    unsigned short* Xh  = (unsigned short*)(ws + o); o += (size_t)M * KPAD / 2;
    unsigned short* Lh  = (unsigned short*)(ws + o); o += (size_t)NPADC * KPAD / 2;
    unsigned short* Wh0 = (unsigned short*)(ws + o); o += (size_t)G4H * KPAD / 2;
    float* numG  = ws + o; o += (size_t)M * NPADC;

    hipMemsetAsync(flags0, 0, 1024 * FSTR * sizeof(int), stream);

    k_lab<<<NPADC, 64, 0, stream>>>(label, ln, Lh);
    k_gather<<<M / 4, 256, 0, stream>>>(seq, emb, Xh, en);
    k_cvtw<<<512, 256, 0, stream>>>(w_ih0, Wh0);

    // merged GEMM: G0 (16 N-tiles) + cos numerator (2 N-tiles)
    k_gmm_all<<<dim3(18, M / 128), 256, 0, stream>>>(Xh, Wh0, Lh, b_ih0, b_hh0, G0, numG);
    k_match<<<dim3(NCLS, BATCH), 256, 0, stream>>>(numG, en, ln, match);

    // pipelined 2-layer recurrence (per-wave publish, 2 barriers/step)
    k_lstm_pipe<<<192, 512, 0, stream>>>(w_hh0, G0, w_ih1, w_hh1, b_ih1, b_hh1,
                                         ring0, ring1, h1last, flags0, flags1);

    k_small<<<dim3(BATCH, HID / 64), 64, 0, stream>>>(h1last, lin_w, lin_b, feat, HID, HID);
    k_small<<<dim3(BATCH, 1), 64, 0, stream>>>(feat, out_w, out_b, lout, NCLS, HID);
    k_final<<<BATCH, 64, 0, stream>>>(match, lout, pred_w, pred_b, (float*)d_out);
}

// Round 22
// 832.195 us; speedup vs baseline: 1.2764x; 1.2764x over previous
//
#include <hip/hip_runtime.h>
#include <hip/hip_bf16.h>
#include <hip/hip_fp16.h>
#include <math.h>

#define S_LEN 256
#define BATCH 64
#define EMB 300
#define HID 512
#define NCLS 46
#define NVAL 4
#define G4H 2048
#define KPAD 320
#define NPADC 256
#define EPSV 1e-8f
#define FSTR 16   // ints per flag slot (64B line)

using half8   = __attribute__((ext_vector_type(8))) _Float16;
using floatx4 = __attribute__((ext_vector_type(4))) float;

__device__ __forceinline__ float fsigm(float x) { return 1.f / (1.f + __expf(-x)); }
__device__ __forceinline__ float ftanh(float x) {
    float e2 = __expf(-2.f * x);
    return (1.f - e2) / (1.f + e2);
}
__device__ __forceinline__ float h2f(unsigned short u) {
    union { unsigned short s; _Float16 h; } cv; cv.s = u; return (float)cv.h;
}
__device__ __forceinline__ half8 pack8(const float* p) {
    float4 f0 = *(const float4*)p;
    float4 f1 = *(const float4*)(p + 4);
    half8 h;
    h[0] = (_Float16)f0.x; h[1] = (_Float16)f0.y; h[2] = (_Float16)f0.z; h[3] = (_Float16)f0.w;
    h[4] = (_Float16)f1.x; h[5] = (_Float16)f1.y; h[6] = (_Float16)f1.z; h[7] = (_Float16)f1.w;
    return h;
}
__device__ __forceinline__ void pollflag(const int* fp, int want) {
    int gd = 1 << 20;
    while (__hip_atomic_load(fp, __ATOMIC_RELAXED, __HIP_MEMORY_SCOPE_AGENT) < want && --gd)
        __builtin_amdgcn_s_sleep(1);
}

// ---------------- label: norm + fp16 convert + zero-pad ----------------
__global__ void k_lab(const float* __restrict__ label, float* __restrict__ ln,
                      unsigned short* __restrict__ Lh) {
    int r = blockIdx.x;
    int lane = threadIdx.x;
    float ss = 0.f;
    if (r < NCLS * NVAL) {
        const float* row = label + (size_t)r * EMB;
        for (int e = lane; e < 80; e += 64) {
            ushort4 o = {0, 0, 0, 0};
            if (e < 75) {
                float4 v = *(const float4*)(row + e * 4);
                ss += v.x * v.x + v.y * v.y + v.z * v.z + v.w * v.w;
                union { _Float16 h; unsigned short s; } a, b, cc, d;
                a.h = (_Float16)v.x; b.h = (_Float16)v.y; cc.h = (_Float16)v.z; d.h = (_Float16)v.w;
                o.x = a.s; o.y = b.s; o.z = cc.s; o.w = d.s;
            }
            *(ushort4*)(Lh + (size_t)r * KPAD + e * 4) = o;
        }
        #pragma unroll
        for (int off = 32; off; off >>= 1) ss += __shfl_down(ss, off);
        if (lane == 0) ln[r] = sqrtf(ss);
    } else {
        for (int e = lane; e < 80; e += 64) {
            ushort4 o = {0, 0, 0, 0};
            *(ushort4*)(Lh + (size_t)r * KPAD + e * 4) = o;
        }
    }
}

// ---------------- gather -> fp16 Xh + fp32 norms ----------------
__global__ __launch_bounds__(256) void k_gather(const int* __restrict__ seq,
                                                const float* __restrict__ emb,
                                                unsigned short* __restrict__ Xh,
                                                float* __restrict__ en) {
    int p = blockIdx.x * 4 + (threadIdx.x >> 6);
    int lane = threadIdx.x & 63;
    int row = seq[p];
    const float4* src = (const float4*)(emb + (size_t)row * EMB);
    float ss = 0.f;
    for (int e = lane; e < 80; e += 64) {
        ushort4 o = {0, 0, 0, 0};
        if (e < 75) {
            float4 v = src[e];
            ss += v.x * v.x + v.y * v.y + v.z * v.z + v.w * v.w;
            union { _Float16 h; unsigned short s; } a, b, cc, d;
            a.h = (_Float16)v.x; b.h = (_Float16)v.y; cc.h = (_Float16)v.z; d.h = (_Float16)v.w;
            o.x = a.s; o.y = b.s; o.z = cc.s; o.w = d.s;
        }
        *(ushort4*)(Xh + (size_t)p * KPAD + e * 4) = o;
    }
    #pragma unroll
    for (int off = 32; off; off >>= 1) ss += __shfl_down(ss, off);
    if (lane == 0) en[p] = sqrtf(ss);
}

// ---------------- merged MFMA GEMM: G0 (bx<16) | cos numerator (bx>=16) ----------------
__global__ __launch_bounds__(256) void k_gmm_all(const unsigned short* __restrict__ X,
                                                 const unsigned short* __restrict__ Wh0,
                                                 const unsigned short* __restrict__ Lh,
                                                 const float* __restrict__ b1,
                                                 const float* __restrict__ b2,
                                                 unsigned short* __restrict__ G0,
                                                 float* __restrict__ numG) {
    __shared__ __align__(16) char smem[20480];
    unsigned short (*Xs)[40] = (unsigned short(*)[40])smem;
    unsigned short (*Ws)[40] = (unsigned short(*)[40])(smem + 10240);

    int bx = blockIdx.x;
    bool iscos = bx >= 16;
    const unsigned short* W = iscos ? Lh : Wh0;
    int n0 = (iscos ? bx - 16 : bx) * 128;
    int m0 = blockIdx.y * 128;
    int tid = threadIdx.x;
    int w8 = tid >> 6, l = tid & 63, lj = l & 15, q8 = l >> 4;
    int wm = w8 & 1, wn = w8 >> 1;

    floatx4 acc[4][4];
    #pragma unroll
    for (int i = 0; i < 4; i++)
        #pragma unroll
        for (int j = 0; j < 4; j++) acc[i][j] = {0.f, 0.f, 0.f, 0.f};

    for (int k0 = 0; k0 < KPAD; k0 += 32) {
        #pragma unroll
        for (int i = 0; i < 2; i++) {
            int id = i * 256 + tid;
            int r = id >> 2, kc = (id & 3) * 8;
            *(uint4*)&Xs[r][kc] = *(const uint4*)&X[(size_t)(m0 + r) * KPAD + k0 + kc];
            *(uint4*)&Ws[r][kc] = *(const uint4*)&W[(size_t)(n0 + r) * KPAD + k0 + kc];
        }
        __syncthreads();
        half8 A[4], B[4];
        #pragma unroll
        for (int i = 0; i < 4; i++) A[i] = *(const half8*)&Xs[wm * 64 + i * 16 + lj][q8 * 8];
        #pragma unroll
        for (int j = 0; j < 4; j++) B[j] = *(const half8*)&Ws[wn * 64 + j * 16 + lj][q8 * 8];
        #pragma unroll
        for (int i = 0; i < 4; i++)
            #pragma unroll
            for (int j = 0; j < 4; j++)
                acc[i][j] = __builtin_amdgcn_mfma_f32_16x16x32_f16(A[i], B[j], acc[i][j], 0, 0, 0);
        __syncthreads();
    }

    #pragma unroll
    for (int j = 0; j < 4; j++) {
        int col = n0 + wn * 64 + j * 16 + lj;
        float bsum = iscos ? 0.f : (b1[col] + b2[col]);
        #pragma unroll
        for (int i = 0; i < 4; i++) {
            int row = m0 + wm * 64 + i * 16 + q8 * 4;
            #pragma unroll
            for (int reg = 0; reg < 4; reg++) {
                float v = acc[i][j][reg] + bsum;
                if (iscos) {
                    numG[(size_t)(row + reg) * NPADC + col] = v;
                } else {
                    union { _Float16 h; unsigned short s; } cv; cv.h = (_Float16)v;
                    G0[(size_t)(row + reg) * G4H + col] = cv.s;
                }
            }
        }
    }
}

// ---------------- match: max over (s,v) of num/(en*ln) ----------------
__global__ __launch_bounds__(256) void k_match(const float* __restrict__ num,
                                               const float* __restrict__ en,
                                               const float* __restrict__ ln,
                                               float* __restrict__ match) {
    int c = blockIdx.x, b = blockIdx.y;
    __shared__ float red[256];
    int s = threadIdx.x;
    float4 nv = *(const float4*)&num[((size_t)s * BATCH + b) * NPADC + c * 4];
    float enb = en[s * BATCH + b];
    float l0 = ln[c * 4 + 0], l1 = ln[c * 4 + 1], l2 = ln[c * 4 + 2], l3 = ln[c * 4 + 3];
    float m = nv.x / fmaxf(enb * l0, EPSV);
    m = fmaxf(m, nv.y / fmaxf(enb * l1, EPSV));
    m = fmaxf(m, nv.z / fmaxf(enb * l2, EPSV));
    m = fmaxf(m, nv.w / fmaxf(enb * l3, EPSV));
    red[s] = m;
    __syncthreads();
    for (int st = 128; st; st >>= 1) {
        if (s < st) red[s] = fmaxf(red[s], red[s + st]);
        __syncthreads();
    }
    if (s == 0) match[b * NCLS + c] = red[0];
}

// ---------------- fused 2-layer pipelined persistent LSTM (R20-verbatim) ----------------
// Per-thread poll->stage fusion; 3 barriers/step; padded flags; setprio.
__global__ __launch_bounds__(512) void k_lstm_pipe(
    const float* __restrict__ w_hh0,
    const unsigned short* __restrict__ G0,   // [256][64][2048] fp16
    const float* __restrict__ w_ih1,
    const float* __restrict__ w_hh1,
    const float* __restrict__ b_ih1,
    const float* __restrict__ b_hh1,
    unsigned short* __restrict__ ring0,
    unsigned short* __restrict__ ring1,
    float* __restrict__ hlast,
    int* __restrict__ flags0,                // [64*FSTR]
    int* __restrict__ flags1)                // [128*FSTR]
{
    __shared__ __align__(16) char smem_raw[24576];
    int bid = blockIdx.x;
    int g = bid & 7;
    int tid = threadIdx.x;
    int w8 = tid >> 6, l = tid & 63, lj = l & 15, q8 = l >> 4;

    if (bid < 64) {
        // ================= LAYER 0 =================
        int r = bid >> 3;
        _Float16 (*hl)[520] = (_Float16(*)[520])smem_raw;
        float (*gbuf)[260] = (float(*)[260])(smem_raw + 8320);

        half8 B0[16], B1[16];
        {
            int lc0 = w8 * 32 + lj;
            int lc1 = w8 * 32 + 16 + lj;
            int wr0 = (lc0 >> 6) * 512 + r * 64 + (lc0 & 63);
            int wr1 = (lc1 >> 6) * 512 + r * 64 + (lc1 & 63);
            #pragma unroll
            for (int kk = 0; kk < 16; kk++) {
                B0[kk] = pack8(w_hh0 + (size_t)wr0 * 512 + kk * 32 + q8 * 8);
                B1[kk] = pack8(w_hh0 + (size_t)wr1 * 512 + kk * 32 + q8 * 8);
            }
        }
        int gb_ = tid >> 6, gj = tid & 63;
        int sb = tid >> 6, sk = (tid & 63) * 8;      // staging slice
        const int* myflag0 = flags0 + (g * 8 + (sk >> 6)) * FSTR;  // source role of my slice
        float cst = 0.f;

        for (int t = 0; t < S_LEN; t++) {
            const unsigned short* Gp = G0 + ((size_t)t * BATCH + g * 8 + gb_) * G4H + r * 64 + gj;
            float gv0 = h2f(Gp[0]), gv1 = h2f(Gp[512]), gv2 = h2f(Gp[1024]), gv3 = h2f(Gp[1536]);

            if (t > 0) {
                // per-thread: poll own source role, then load (no barrier between)
                pollflag(myflag0, t);
                {
                    const unsigned long long* src = (const unsigned long long*)
                        (ring0 + ((size_t)(t - 1) * BATCH + g * 8 + sb) * HID + sk);
                    unsigned long long v0 = __hip_atomic_load(src,     __ATOMIC_RELAXED, __HIP_MEMORY_SCOPE_AGENT);
                    unsigned long long v1 = __hip_atomic_load(src + 1, __ATOMIC_RELAXED, __HIP_MEMORY_SCOPE_AGENT);
                    *(unsigned long long*)&hl[sb][sk]     = v0;
                    *(unsigned long long*)&hl[sb][sk + 4] = v1;
                }
                __syncthreads();
                floatx4 acc0 = {0.f, 0.f, 0.f, 0.f}, acc1 = {0.f, 0.f, 0.f, 0.f};
                __builtin_amdgcn_s_setprio(1);
                #pragma unroll
                for (int kk = 0; kk < 16; kk++) {
                    half8 A = *(const half8*)&hl[l & 7][kk * 32 + q8 * 8];
                    acc0 = __builtin_amdgcn_mfma_f32_16x16x32_f16(A, B0[kk], acc0, 0, 0, 0);
                    acc1 = __builtin_amdgcn_mfma_f32_16x16x32_f16(A, B1[kk], acc1, 0, 0, 0);
                }
                __builtin_amdgcn_s_setprio(0);
                if (l < 32) {
                    #pragma unroll
                    for (int ri = 0; ri < 4; ri++) {
                        int row = q8 * 4 + ri;
                        gbuf[row][w8 * 32 + lj]      = acc0[ri];
                        gbuf[row][w8 * 32 + 16 + lj] = acc1[ri];
                    }
                }
                __syncthreads();
            }

            float s_i = gv0 + (t ? gbuf[gb_][gj]       : 0.f);
            float s_f = gv1 + (t ? gbuf[gb_][64 + gj]  : 0.f);
            float s_g = gv2 + (t ? gbuf[gb_][128 + gj] : 0.f);
            float s_o = gv3 + (t ? gbuf[gb_][192 + gj] : 0.f);
            cst = fsigm(s_f) * cst + fsigm(s_i) * ftanh(s_g);
            float hv = fsigm(s_o) * ftanh(cst);

            union { unsigned short s; _Float16 h; } cv; cv.h = (_Float16)hv;
            unsigned int mine = cv.s;
            unsigned int other = (unsigned int)__shfl_xor((int)mine, 1);
            if (!(gj & 1)) {
                unsigned int pk = (mine & 0xFFFFu) | (other << 16);
                unsigned int* rp = (unsigned int*)ring0;
                __hip_atomic_store(rp + (((size_t)t * BATCH + g * 8 + gb_) * HID + r * 64 + gj) / 2,
                                   pk, __ATOMIC_RELAXED, __HIP_MEMORY_SCOPE_AGENT);
            }
            __syncthreads();   // drains ring stores
            if (tid == 0)
                __hip_atomic_store(flags0 + (g * 8 + r) * FSTR, t + 1, __ATOMIC_RELAXED, __HIP_MEMORY_SCOPE_AGENT);
        }
    } else {
        // ================= LAYER 1 =================
        int rid = (bid - 64) >> 3;
        _Float16 (*hl0)[520] = (_Float16(*)[520])smem_raw;
        _Float16 (*hl1)[520] = (_Float16(*)[520])(smem_raw + 8320);
        float (*gbuf)[132] = (float(*)[132])(smem_raw + 16640);

        half8 Bin[16], Brec[16];
        {
            int gate = w8 >> 1;
            int wrow = gate * 512 + rid * 32 + (w8 & 1) * 16 + lj;
            #pragma unroll
            for (int kk = 0; kk < 16; kk++) {
                Bin[kk]  = pack8(w_ih1 + (size_t)wrow * 512 + kk * 32 + q8 * 8);
                Brec[kk] = pack8(w_hh1 + (size_t)wrow * 512 + kk * 32 + q8 * 8);
            }
        }
        float bi = 0.f, bf = 0.f, bgg = 0.f, bo = 0.f;
        if (tid < 256) {
            int u = tid & 31;
            int base = rid * 32 + u;
            bi  = b_ih1[base]        + b_hh1[base];
            bf  = b_ih1[512 + base]  + b_hh1[512 + base];
            bgg = b_ih1[1024 + base] + b_hh1[1024 + base];
            bo  = b_ih1[1536 + base] + b_hh1[1536 + base];
        }
        int sb = tid >> 6, sk = (tid & 63) * 8;
        const int* myflag0 = flags0 + (g * 8  + (sk >> 6)) * FSTR;   // h0 source role (64 units)
        const int* myflag1 = flags1 + (g * 16 + (sk >> 5)) * FSTR;   // h1 source role (32 units)
        float cst = 0.f;

        for (int t = 0; t < S_LEN; t++) {
            // per-thread poll of both source roles, then both loads
            pollflag(myflag0, t + 1);
            if (t > 0) pollflag(myflag1, t);
            {
                const unsigned long long* s0 = (const unsigned long long*)
                    (ring0 + ((size_t)t * BATCH + g * 8 + sb) * HID + sk);
                unsigned long long v0 = __hip_atomic_load(s0,     __ATOMIC_RELAXED, __HIP_MEMORY_SCOPE_AGENT);
                unsigned long long v1 = __hip_atomic_load(s0 + 1, __ATOMIC_RELAXED, __HIP_MEMORY_SCOPE_AGENT);
                *(unsigned long long*)&hl0[sb][sk]     = v0;
                *(unsigned long long*)&hl0[sb][sk + 4] = v1;
                if (t > 0) {
                    const unsigned long long* s1 = (const unsigned long long*)
                        (ring1 + ((size_t)(t - 1) * BATCH + g * 8 + sb) * HID + sk);
                    unsigned long long u0 = __hip_atomic_load(s1,     __ATOMIC_RELAXED, __HIP_MEMORY_SCOPE_AGENT);
                    unsigned long long u1 = __hip_atomic_load(s1 + 1, __ATOMIC_RELAXED, __HIP_MEMORY_SCOPE_AGENT);
                    *(unsigned long long*)&hl1[sb][sk]     = u0;
                    *(unsigned long long*)&hl1[sb][sk + 4] = u1;
                }
            }
            __syncthreads();

            floatx4 accA = {0.f, 0.f, 0.f, 0.f}, accB = {0.f, 0.f, 0.f, 0.f};
            __builtin_amdgcn_s_setprio(1);
            #pragma unroll
            for (int kk = 0; kk < 16; kk++) {
                half8 A0 = *(const half8*)&hl0[l & 7][kk * 32 + q8 * 8];
                accA = __builtin_amdgcn_mfma_f32_16x16x32_f16(A0, Bin[kk], accA, 0, 0, 0);
            }
            if (t > 0) {
                #pragma unroll
                for (int kk = 0; kk < 16; kk++) {
                    half8 A1 = *(const half8*)&hl1[l & 7][kk * 32 + q8 * 8];
                    accB = __builtin_amdgcn_mfma_f32_16x16x32_f16(A1, Brec[kk], accB, 0, 0, 0);
                }
            }
            __builtin_amdgcn_s_setprio(0);
            if (l < 32) {
                #pragma unroll
                for (int ri = 0; ri < 4; ri++) {
                    int row = q8 * 4 + ri;
                    gbuf[row][w8 * 16 + lj] = accA[ri] + accB[ri];
                }
            }
            __syncthreads();

            if (tid < 256) {
                int b = tid >> 5, u = tid & 31;
                float s_i = gbuf[b][u]      + bi;
                float s_f = gbuf[b][32 + u] + bf;
                float s_g = gbuf[b][64 + u] + bgg;
                float s_o = gbuf[b][96 + u] + bo;
                cst = fsigm(s_f) * cst + fsigm(s_i) * ftanh(s_g);
                float hv = fsigm(s_o) * ftanh(cst);

                union { unsigned short s; _Float16 h; } cv; cv.h = (_Float16)hv;
                unsigned int mine = cv.s;
                unsigned int other = (unsigned int)__shfl_xor((int)mine, 1);
                if (!(u & 1)) {
                    unsigned int pk = (mine & 0xFFFFu) | (other << 16);
                    unsigned int* rp = (unsigned int*)ring1;
                    __hip_atomic_store(rp + (((size_t)t * BATCH + g * 8 + b) * HID + rid * 32 + u) / 2,
                                       pk, __ATOMIC_RELAXED, __HIP_MEMORY_SCOPE_AGENT);
                }
                if (t == S_LEN - 1)
                    hlast[(g * 8 + b) * HID + rid * 32 + u] = hv;
            }
            __syncthreads();   // drains ring stores
            if (tid == 0)
                __hip_atomic_store(flags1 + (g * 16 + rid) * FSTR, t + 1, __ATOMIC_RELAXED, __HIP_MEMORY_SCOPE_AGENT);
        }
    }
}

// ---------------- small GEMM ----------------
__global__ void k_small(const float* __restrict__ X, const float* __restrict__ W,
                        const float* __restrict__ bias, float* __restrict__ Y,
                        int N, int K) {
    int m = blockIdx.x;
    int n = blockIdx.y * 64 + threadIdx.x;
    if (n >= N) return;
    const float* x = X + (size_t)m * K;
    const float* w = W + (size_t)n * K;
    float s = bias[n];
    for (int k = 0; k < K; k++) s += x[k] * w[k];
    Y[(size_t)m * N + n] = s;
}

// ---------------- final head ----------------
__global__ void k_final(const float* __restrict__ match, const float* __restrict__ lout,
                        const float* __restrict__ W, const float* __restrict__ bias,
                        float* __restrict__ out) {
    int m = blockIdx.x;
    int n = threadIdx.x;
    if (n >= NCLS) return;
    const float* w = W + (size_t)n * (2 * NCLS);
    float s = bias[n];
    for (int k = 0; k < NCLS; k++) s += match[m * NCLS + k] * w[k];
    for (int k = 0; k < NCLS; k++) s += lout[m * NCLS + k] * w[NCLS + k];
    out[m * NCLS + n] = s;
}

// ---------------- w_ih0 fp32[2048][300] -> fp16[2048][320] zero-padded ----------------
__global__ __launch_bounds__(256) void k_cvtw(const float* __restrict__ in,
                                              unsigned short* __restrict__ out) {
    int r = blockIdx.x * 4 + (threadIdx.x >> 6);
    int lane = threadIdx.x & 63;
    for (int e = lane; e < 80; e += 64) {
        int c = e * 4;
        ushort4 o = {0, 0, 0, 0};
        if (c < EMB) {
            float4 v = *(const float4*)(in + (size_t)r * EMB + c);
            union { _Float16 h; unsigned short s; } a, b, cc, d;
            a.h = (_Float16)v.x; b.h = (_Float16)v.y; cc.h = (_Float16)v.z; d.h = (_Float16)v.w;
            o.x = a.s; o.y = b.s; o.z = cc.s; o.w = d.s;
        }
        *(ushort4*)(out + (size_t)r * KPAD + c) = o;
    }
}

extern "C" void kernel_launch(void* const* d_in, const int* in_sizes, int n_in,
                              void* d_out, int out_size, void* d_ws, size_t ws_size,
                              hipStream_t stream) {
    (void)in_sizes; (void)n_in; (void)out_size; (void)ws_size;
    const int*   seq    = (const int*)d_in[0];
    const float* emb    = (const float*)d_in[1];
    const float* w_ih0  = (const float*)d_in[2];
    const float* w_hh0  = (const float*)d_in[3];
    const float* b_ih0  = (const float*)d_in[4];
    const float* b_hh0  = (const float*)d_in[5];
    const float* w_ih1  = (const float*)d_in[6];
    const float* w_hh1  = (const float*)d_in[7];
    const float* b_ih1  = (const float*)d_in[8];
    const float* b_hh1  = (const float*)d_in[9];
    const float* lin_w  = (const float*)d_in[10];
    const float* lin_b  = (const float*)d_in[11];
    const float* out_w  = (const float*)d_in[12];
    const float* out_b  = (const float*)d_in[13];
    const float* pred_w = (const float*)d_in[14];
    const float* pred_b = (const float*)d_in[15];
    const float* label  = (const float*)d_in[16];

    const int M = S_LEN * BATCH;  // 16384
    float* ws = (float*)d_ws;
    size_t o = 0;
    unsigned short* G0 = (unsigned short*)(ws + o); o += (size_t)M * G4H / 2;
    unsigned short* ring0 = (unsigned short*)(ws + o); o += (size_t)M * HID / 2;
    unsigned short* ring1 = (unsigned short*)(ws + o); o += (size_t)M * HID / 2;
    float* h1last = ws + o; o += (size_t)BATCH * HID;
    float* en    = ws + o; o += M;
    float* ln    = ws + o; o += 256;
    float* match = ws + o; o += 3072;
    float* feat  = ws + o; o += (size_t)BATCH * HID;
    float* lout  = ws + o; o += 3072;
    int*   flags0 = (int*)(ws + o); o += 64 * FSTR;
    int*   flags1 = (int*)(ws + o); o += 128 * FSTR;
    unsigned short* Xh  = (unsigned short*)(ws + o); o += (size_t)M * KPAD / 2;
    unsigned short* Lh  = (unsigned short*)(ws + o); o += (size_t)NPADC * KPAD / 2;
    unsigned short* Wh0 = (unsigned short*)(ws + o); o += (size_t)G4H * KPAD / 2;
    float* numG  = ws + o; o += (size_t)M * NPADC;

    hipMemsetAsync(flags0, 0, 192 * FSTR * sizeof(int), stream);

    k_lab<<<NPADC, 64, 0, stream>>>(label, ln, Lh);
    k_gather<<<M / 4, 256, 0, stream>>>(seq, emb, Xh, en);
    k_cvtw<<<512, 256, 0, stream>>>(w_ih0, Wh0);

    // merged GEMM: G0 (16 N-tiles) + cos numerator (2 N-tiles)
    k_gmm_all<<<dim3(18, M / 128), 256, 0, stream>>>(Xh, Wh0, Lh, b_ih0, b_hh0, G0, numG);
    k_match<<<dim3(NCLS, BATCH), 256, 0, stream>>>(numG, en, ln, match);

    // pipelined 2-layer recurrence (per-thread poll->stage, 3 barriers/step)
    k_lstm_pipe<<<192, 512, 0, stream>>>(w_hh0, G0, w_ih1, w_hh1, b_ih1, b_hh1,
                                         ring0, ring1, h1last, flags0, flags1);

    k_small<<<dim3(BATCH, HID / 64), 64, 0, stream>>>(h1last, lin_w, lin_b, feat, HID, HID);
    k_small<<<dim3(BATCH, 1), 64, 0, stream>>>(feat, out_w, out_b, lout, NCLS, HID);
    k_final<<<BATCH, 64, 0, stream>>>(match, lout, pred_w, pred_b, (float*)d_out);
}